// Round 2
// baseline (4842.305 us; speedup 1.0000x reference)
//
#include <hip/hip_runtime.h>

// Sizes (fixed by the problem)
#define TT 256
#define BB 32
#define EE 512
#define HH 256
#define GG 1024   // 4*H
#define NK 17

// ---------------------------------------------------------------- embedding
__global__ void k_embed(const int* __restrict__ src,
                        const float* __restrict__ emb,
                        float* __restrict__ xin) {
  int row = blockIdx.x;                 // b*T + t, 8192 rows
  int v = src[row];                     // emb[0] is all-zero, so padding is fine
  const float4* e = reinterpret_cast<const float4*>(emb + (size_t)v * EE);
  float4* o = reinterpret_cast<float4*>(xin + (size_t)row * EE);
  o[threadIdx.x] = e[threadIdx.x];      // 128 threads * 16B = 2048B = 512 f32
}

// ------------------------------------------------- Whh transpose -> f32 [h][4H]
__global__ void k_prep_whhT(const float* __restrict__ whh,
                            float* __restrict__ whhT) {
  int idx = blockIdx.x * 256 + threadIdx.x;   // < 2*2*256*1024 = 1048576
  int g = idx & 1023;
  int h = (idx >> 10) & 255;
  int ld = idx >> 18;                         // l*2+d
  whhT[idx] = whh[((size_t)(ld * GG + g)) * HH + h];
}

__global__ void k_prep_bias(const float* __restrict__ bih,
                            const float* __restrict__ bhh,
                            float* __restrict__ bias) {
  int i = blockIdx.x * 256 + threadIdx.x;     // < 4096
  bias[i] = bih[i] + bhh[i];
}

// ------------------------------------------------------------- xg GEMM
// out[m][g] = sum_k X[m][k]*W[g][k] + bias[g];  M=8192, N=1024, K=512
__global__ __launch_bounds__(256) void k_gemm(
    const float* __restrict__ X,    // [8192][512] f32
    const float* __restrict__ W,    // [1024][512] f32 (row g)
    const float* __restrict__ bias, // [1024]
    float* __restrict__ out) {      // [8192][1024] f32
  __shared__ float Xs[32][68];   // [k][m], padded
  __shared__ float Ws[32][68];   // [k][n]
  const int tid = threadIdx.x;
  const int tx = tid & 15, ty = tid >> 4;
  const int m0 = blockIdx.y * 64, n0 = blockIdx.x * 64;
  const int lr = tid >> 2;          // 0..63
  const int lc = (tid & 3) * 8;     // 0,8,16,24
  float acc[4][4] = {};
  for (int k0 = 0; k0 < EE; k0 += 32) {
    float4 xa = *reinterpret_cast<const float4*>(X + (size_t)(m0 + lr) * EE + k0 + lc);
    float4 xb = *reinterpret_cast<const float4*>(X + (size_t)(m0 + lr) * EE + k0 + lc + 4);
    float4 wa = *reinterpret_cast<const float4*>(W + (size_t)(n0 + lr) * EE + k0 + lc);
    float4 wb = *reinterpret_cast<const float4*>(W + (size_t)(n0 + lr) * EE + k0 + lc + 4);
    Xs[lc + 0][lr] = xa.x; Xs[lc + 1][lr] = xa.y; Xs[lc + 2][lr] = xa.z; Xs[lc + 3][lr] = xa.w;
    Xs[lc + 4][lr] = xb.x; Xs[lc + 5][lr] = xb.y; Xs[lc + 6][lr] = xb.z; Xs[lc + 7][lr] = xb.w;
    Ws[lc + 0][lr] = wa.x; Ws[lc + 1][lr] = wa.y; Ws[lc + 2][lr] = wa.z; Ws[lc + 3][lr] = wa.w;
    Ws[lc + 4][lr] = wb.x; Ws[lc + 5][lr] = wb.y; Ws[lc + 6][lr] = wb.z; Ws[lc + 7][lr] = wb.w;
    __syncthreads();
#pragma unroll
    for (int k = 0; k < 32; ++k) {
      float4 a = *reinterpret_cast<const float4*>(&Xs[k][ty * 4]);
      float4 b = *reinterpret_cast<const float4*>(&Ws[k][tx * 4]);
      float av[4] = {a.x, a.y, a.z, a.w};
      float bv[4] = {b.x, b.y, b.z, b.w};
#pragma unroll
      for (int i = 0; i < 4; ++i)
#pragma unroll
        for (int j = 0; j < 4; ++j) acc[i][j] = fmaf(av[i], bv[j], acc[i][j]);
    }
    __syncthreads();
  }
  const int n = n0 + tx * 4;
#pragma unroll
  for (int i = 0; i < 4; ++i) {
    float4 o;
    o.x = acc[i][0] + bias[n + 0];
    o.y = acc[i][1] + bias[n + 1];
    o.z = acc[i][2] + bias[n + 2];
    o.w = acc[i][3] + bias[n + 3];
    *reinterpret_cast<float4*>(out + (size_t)(m0 + ty * 4 + i) * GG + n) = o;
  }
}

// ------------------------------------------------------------- LSTM recurrence
// One block per (batch, dir); 256 threads; 256 sequential steps.
__global__ __launch_bounds__(256) void k_rec(
    const float* __restrict__ xg,      // [2][8192][1024] (dir-major), bias included
    const float* __restrict__ whhT,    // [2][256][1024] f32, this layer
    const int* __restrict__ lens,      // [32]
    float* __restrict__ outx)          // [8192][512] f32: [:256]=fwd, [256:]=bwd
{
  const int b = blockIdx.x & 31;
  const int dir = blockIdx.x >> 5;
  const int j = threadIdx.x;           // h index / gate quad
  const float* xgb = xg + ((size_t)dir * (BB * TT) + (size_t)b * TT) * GG;
  const float* wT = whhT + (size_t)dir * HH * GG + 4 * j;
  __shared__ float hsh[HH];
  __shared__ float gates[GG];
  float c = 0.f;
  hsh[j] = 0.f;
  __syncthreads();
  const int len = lens[b];
  for (int s = 0; s < TT; ++s) {
    const int t = dir ? (TT - 1 - s) : s;
    float4 acc = *reinterpret_cast<const float4*>(xgb + (size_t)t * GG + 4 * j);
    const float4* hp = reinterpret_cast<const float4*>(hsh);
#pragma unroll 4
    for (int h4 = 0; h4 < 64; ++h4) {
      float4 hv = hp[h4];
      const float* w0 = wT + (size_t)h4 * (4 * GG);
      float4 wa = *reinterpret_cast<const float4*>(w0);
      float4 wb = *reinterpret_cast<const float4*>(w0 + GG);
      float4 wc = *reinterpret_cast<const float4*>(w0 + 2 * GG);
      float4 wd = *reinterpret_cast<const float4*>(w0 + 3 * GG);
      acc.x = fmaf(hv.x, wa.x, acc.x); acc.y = fmaf(hv.x, wa.y, acc.y);
      acc.z = fmaf(hv.x, wa.z, acc.z); acc.w = fmaf(hv.x, wa.w, acc.w);
      acc.x = fmaf(hv.y, wb.x, acc.x); acc.y = fmaf(hv.y, wb.y, acc.y);
      acc.z = fmaf(hv.y, wb.z, acc.z); acc.w = fmaf(hv.y, wb.w, acc.w);
      acc.x = fmaf(hv.z, wc.x, acc.x); acc.y = fmaf(hv.z, wc.y, acc.y);
      acc.z = fmaf(hv.z, wc.z, acc.z); acc.w = fmaf(hv.z, wc.w, acc.w);
      acc.x = fmaf(hv.w, wd.x, acc.x); acc.y = fmaf(hv.w, wd.y, acc.y);
      acc.z = fmaf(hv.w, wd.z, acc.z); acc.w = fmaf(hv.w, wd.w, acc.w);
    }
    *reinterpret_cast<float4*>(&gates[4 * j]) = acc;
    __syncthreads();
    float gi = gates[j], gf = gates[HH + j], gg = gates[2 * HH + j], go = gates[3 * HH + j];
    float iv = 1.f / (1.f + expf(-gi));
    float fv = 1.f / (1.f + expf(-gf));
    float gv = tanhf(gg);
    float ov = 1.f / (1.f + expf(-go));
    float cn = fv * c + iv * gv;
    float hn = ov * tanhf(cn);
    const bool m = (t < len);
    outx[(size_t)(b * TT + t) * (2 * HH) + dir * HH + j] = m ? hn : 0.f;
    if (m) { c = cn; hsh[j] = hn; }   // safe: reads of hsh for this step finished before sync above
    __syncthreads();
  }
}

// ------------------------------------------------------------- logits
__global__ __launch_bounds__(256) void k_logits(
    const float* __restrict__ feats,  // [8192][512] f32
    const float* __restrict__ wlin,   // [17][512] f32
    const float* __restrict__ blin,   // [17]
    float* __restrict__ logits) {     // [8192][17]
  int o = blockIdx.x * 256 + threadIdx.x;      // < 8192*17 = 139264 exactly
  int m = o / NK, jj = o - m * NK;
  const float4* fr = reinterpret_cast<const float4*>(feats + (size_t)m * EE);
  const float4* wr = reinterpret_cast<const float4*>(wlin + (size_t)jj * EE);
  float s = blin[jj];
  for (int q = 0; q < EE / 4; ++q) {
    float4 fv = fr[q], wv = wr[q];
    s = fmaf(fv.x, wv.x, s);
    s = fmaf(fv.y, wv.y, s);
    s = fmaf(fv.z, wv.z, s);
    s = fmaf(fv.w, wv.w, s);
  }
  logits[o] = s;
}

// ------------------------------------------------------------- CRF NLL per batch
__global__ __launch_bounds__(64) void k_crf(
    const float* __restrict__ logits,   // [32][256][17]
    const int* __restrict__ labels,     // [32][256]
    const int* __restrict__ lens,       // [32]
    const float* __restrict__ trans,    // [17][17]
    const float* __restrict__ startv,   // [17]
    const float* __restrict__ endv,     // [17]
    float* __restrict__ res) {          // [32] = numerator - partition
  const int b = blockIdx.x;
  const int tid = threadIdx.x;          // one wave
  __shared__ float trs[NK * NK];
  __shared__ float alpha[NK];
  for (int i = tid; i < NK * NK; i += 64) trs[i] = trans[i];
  const int len = lens[b];
  const int* lab = labels + b * TT;
  const float* lg = logits + (size_t)b * TT * NK;
  // numerator: emission + transition sums (lane-parallel over t)
  float part = 0.f;
  for (int t = tid; t < TT; t += 64)
    if (t < len) part += lg[t * NK + lab[t]];
  __syncthreads();
  for (int t = tid; t < TT - 1; t += 64)
    if (t + 1 < len) part += trs[lab[t] * NK + lab[t + 1]];
#pragma unroll
  for (int off = 32; off > 0; off >>= 1) part += __shfl_down(part, off);
  // forward algorithm (alpha in LDS, lanes 0..16 own a tag each)
  if (tid < NK) alpha[tid] = startv[tid] + lg[tid];
  __syncthreads();
  const int tmax = (len < TT) ? len : TT;   // steps with mask==false leave alpha unchanged
  for (int t = 1; t < tmax; ++t) {
    float nv = 0.f;
    if (tid < NK) {
      float mx = -1e30f;
#pragma unroll
      for (int i = 0; i < NK; ++i) mx = fmaxf(mx, alpha[i] + trs[i * NK + tid]);
      float sum = 0.f;
#pragma unroll
      for (int i = 0; i < NK; ++i) sum += expf(alpha[i] + trs[i * NK + tid] - mx);
      nv = mx + logf(sum) + lg[t * NK + tid];
    }
    __syncthreads();
    if (tid < NK) alpha[tid] = nv;
    __syncthreads();
  }
  if (tid == 0) {
    float mx = -1e30f;
    float av[NK];
    for (int i = 0; i < NK; ++i) { av[i] = alpha[i] + endv[i]; mx = fmaxf(mx, av[i]); }
    float sum = 0.f;
    for (int i = 0; i < NK; ++i) sum += expf(av[i] - mx);
    float partition = mx + logf(sum);
    float numer = startv[lab[0]] + part + endv[lab[len - 1]];
    res[b] = numer - partition;
  }
}

__global__ void k_final(const float* __restrict__ res, float* __restrict__ out) {
  int tid = threadIdx.x;  // 64
  float v = (tid < BB) ? res[tid] : 0.f;
#pragma unroll
  for (int off = 32; off > 0; off >>= 1) v += __shfl_down(v, off);
  if (tid == 0) out[0] = -v;
}

extern "C" void kernel_launch(void* const* d_in, const int* in_sizes, int n_in,
                              void* d_out, int out_size, void* d_ws, size_t ws_size,
                              hipStream_t stream) {
  const int* src = (const int*)d_in[0];
  const int* lens = (const int*)d_in[1];
  const int* labels = (const int*)d_in[2];
  // d_in[3] = decode (always 0, ignored)
  const float* emb = (const float*)d_in[4];
  const float* Wih = (const float*)d_in[5];
  const float* Whh = (const float*)d_in[6];
  const float* bih = (const float*)d_in[7];
  const float* bhh = (const float*)d_in[8];
  const float* Wlin = (const float*)d_in[9];
  const float* blin = (const float*)d_in[10];
  const float* trans = (const float*)d_in[11];
  const float* startv = (const float*)d_in[12];
  const float* endv = (const float*)d_in[13];

  char* w = (char*)d_ws;
  float* xin0 = (float*)w;  w += (size_t)BB * TT * EE * 4;        // 16.8 MB
  float* xin1 = (float*)w;  w += (size_t)BB * TT * EE * 4;        // 16.8 MB
  float* xg = (float*)w;    w += (size_t)2 * BB * TT * GG * 4;    // 67.1 MB
  float* whhT = (float*)w;  w += (size_t)2 * 2 * HH * GG * 4;     // 8.39 MB
  float* biasb = (float*)w; w += (size_t)2 * 2 * GG * 4;          // 16 KB
  float* logits = (float*)w; w += (size_t)BB * TT * NK * 4;       // 557 KB
  float* res = (float*)w;   w += BB * 4;

  k_embed<<<BB * TT, 128, 0, stream>>>(src, emb, xin0);
  k_prep_whhT<<<(2 * 2 * HH * GG) / 256, 256, 0, stream>>>(Whh, whhT);
  k_prep_bias<<<16, 256, 0, stream>>>(bih, bhh, biasb);

  for (int l = 0; l < 2; ++l) {
    const float* xin = l ? xin1 : xin0;
    float* xout = l ? xin0 : xin1;
    for (int d = 0; d < 2; ++d) {
      k_gemm<<<dim3(GG / 64, (BB * TT) / 64), 256, 0, stream>>>(
          xin, Wih + ((size_t)(l * 2 + d)) * GG * EE,
          biasb + (l * 2 + d) * GG, xg + (size_t)d * BB * TT * GG);
    }
    k_rec<<<64, 256, 0, stream>>>(xg, whhT + (size_t)l * 2 * HH * GG, lens, xout);
  }

  k_logits<<<(BB * TT * NK) / 256, 256, 0, stream>>>(xin0, Wlin, blin, logits);
  k_crf<<<BB, 64, 0, stream>>>(logits, labels, lens, trans, startv, endv, res);
  k_final<<<1, 64, 0, stream>>>(res, (float*)d_out);
}